// Round 11
// baseline (2856.540 us; speedup 1.0000x reference)
//
#include <hip/hip_runtime.h>
#include <math.h>

typedef unsigned short u16;
typedef __attribute__((ext_vector_type(8))) short short8;
typedef __attribute__((ext_vector_type(4))) float floatx4;

__device__ __forceinline__ u16 f2b(float f) {
  unsigned u = __float_as_uint(f);
  return (u16)((u + 0x7fffu + ((u >> 16) & 1u)) >> 16);
}

#define NBLK 1024u

// one-shot grid barrier: cnt pre-zeroed by hipMemsetAsync before launch
__device__ __forceinline__ void gsync(unsigned* cnt, int tid) {
  __syncthreads();
  __threadfence();
  if (tid == 0) {
    __hip_atomic_fetch_add(cnt, 1u, __ATOMIC_ACQ_REL, __HIP_MEMORY_SCOPE_AGENT);
    while (__hip_atomic_load(cnt, __ATOMIC_ACQUIRE, __HIP_MEMORY_SCOPE_AGENT) < NBLK) {}
  }
  __syncthreads();
  __threadfence();
}

__global__ __launch_bounds__(256, 4) void mega(
    const float* __restrict__ x, const float* __restrict__ qp, const float* __restrict__ kp,
    const float* __restrict__ wv, const float* __restrict__ wpr, const float* __restrict__ qg,
    const float* __restrict__ w0, const float* __restrict__ g1, const float* __restrict__ b1,
    const float* __restrict__ w1, const float* __restrict__ g2, const float* __restrict__ b2,
    const float* __restrict__ w2, const float* __restrict__ wout, const float* __restrict__ ct,
    float* __restrict__ z, float* __restrict__ ws, unsigned* __restrict__ bar) {
  const int bid = blockIdx.x, tid = threadIdx.x;
  const int lane = tid & 63, wave = tid >> 6;
  const int quad = lane >> 4, l16 = lane & 15;

  const size_t MEG = 1024 * 1024;
  float* A_QKV = ws;                          // [0..4M) qkv fp32; later he0 [0..2M)
  u16* A_Qb = (u16*)(ws + 4 * MEG);
  u16* A_Kb = (u16*)(ws + 4 * MEG + 524288);
  u16* A_Vt = (u16*)(ws + 5 * MEG);
  float* A_HE2 = ws + 4 * MEG;                // alias after attention
  float* A_PO = ws + 6 * MEG;                 // [6M..10M) partial O
  float* A_Y = ws + 6 * MEG;                  // later he1 [6M..8M)
  float* A_H = ws + 8 * MEG;                  // later h [8M..10M)
  u16* A_Y2b = (u16*)(ws + 10 * MEG);
  u16* A_Hb = (u16*)(ws + 11 * MEG);
  u16* A_LNb = (u16*)(ws + 12 * MEG);
  u16* XB = (u16*)(ws + 13 * MEG);
  float* A_PL = ws + 13 * MEG + 917504;       // 64K floats in dead tail of XB region? no:
  // XB occupies [13M..14M) as floats; PL written after XB consumed (S1). Use [13M..13M+128K).
  A_PL = ws + 13 * MEG;
  u16* WCATb = (u16*)(ws + 14 * MEG);
  u16* WPRb = WCATb + 524288;
  u16* W0b = WPRb + 262144;
  u16* W1b = W0b + 262144;
  u16* W2b = W1b + 262144;

  __shared__ __align__(16) u16 SA[4608];  // 64*72
  __shared__ __align__(16) u16 SB[4608];

  // ======== S0: casts (x->bf16, 4 weights, Wcat) ========
  for (int vb = bid; vb < 5120; vb += 1024) {
    if (vb < 2048) {
      int i = vb * 256 + tid;
      float4 v = ((const float4*)x)[i];
      ushort4 o; o.x = f2b(v.x); o.y = f2b(v.y); o.z = f2b(v.z); o.w = f2b(v.w);
      ((ushort4*)XB)[i] = o;
    } else if (vb < 3072) {
      int i = (vb - 2048) * 256 + tid;
      int sel = i >> 16, j = i & 65535;
      const float* s = sel == 0 ? wpr : sel == 1 ? w0 : sel == 2 ? w1 : w2;
      u16* d = sel == 0 ? WPRb : sel == 1 ? W0b : sel == 2 ? W1b : W2b;
      float4 v = ((const float4*)s)[j];
      ushort4 o; o.x = f2b(v.x); o.y = f2b(v.y); o.z = f2b(v.z); o.w = f2b(v.w);
      ((ushort4*)d)[j] = o;
    } else {
      int i = (vb - 3072) * 256 + tid;
      int d = i & 511, c = i >> 9;
      float v;
      if (c < 512) {
        int hh = c >> 5, o = c & 31;
        const float* src = (hh < 8) ? qp : kp;
        int h = hh & 7;
        v = src[(h * 512 + d) * 32 + o];
      } else {
        v = wv[(c - 512) * 512 + d];
      }
      WCATb[i] = f2b(v);
    }
  }
  gsync(&bar[0], tid);

  // ======== S1: QKV GEMM 64x64 (bid -> bn 0..15, bm 0..63), C = A_QKV (N=1024) ========
  {
    u16 (*As)[72] = (u16(*)[72])SA;
    u16 (*Bs)[72] = (u16(*)[72])SB;
    const int bn = bid & 15, bm = bid >> 4;
    const int wm = wave >> 1, wn = wave & 1;
    const int sr = tid >> 2, sk = (tid & 3) << 4;
    floatx4 acc[2][2] = {};
    const u16* Ap = XB + (size_t)(bm * 64 + sr) * 512 + sk;
    const u16* Bp = WCATb + (size_t)(bn * 64 + sr) * 512 + sk;
    uint4 a0 = *(const uint4*)(Ap);
    uint4 a1 = *(const uint4*)(Ap + 8);
    uint4 b0 = *(const uint4*)(Bp);
    uint4 b1 = *(const uint4*)(Bp + 8);
    for (int k0 = 0; k0 < 512; k0 += 64) {
      __syncthreads();
      *(uint4*)&As[sr][sk] = a0;
      *(uint4*)&As[sr][sk + 8] = a1;
      *(uint4*)&Bs[sr][sk] = b0;
      *(uint4*)&Bs[sr][sk + 8] = b1;
      __syncthreads();
      if (k0 + 64 < 512) {
        a0 = *(const uint4*)(Ap + k0 + 64);
        a1 = *(const uint4*)(Ap + k0 + 72);
        b0 = *(const uint4*)(Bp + k0 + 64);
        b1 = *(const uint4*)(Bp + k0 + 72);
      }
#pragma unroll
      for (int kk = 0; kk < 2; kk++) {
        short8 af0 = *(const short8*)&As[wm * 32 + l16][kk * 32 + quad * 8];
        short8 af1 = *(const short8*)&As[wm * 32 + 16 + l16][kk * 32 + quad * 8];
        short8 bf0 = *(const short8*)&Bs[wn * 32 + l16][kk * 32 + quad * 8];
        short8 bf1 = *(const short8*)&Bs[wn * 32 + 16 + l16][kk * 32 + quad * 8];
        acc[0][0] = __builtin_amdgcn_mfma_f32_16x16x32_bf16(af0, bf0, acc[0][0], 0, 0, 0);
        acc[0][1] = __builtin_amdgcn_mfma_f32_16x16x32_bf16(af0, bf1, acc[0][1], 0, 0, 0);
        acc[1][0] = __builtin_amdgcn_mfma_f32_16x16x32_bf16(af1, bf0, acc[1][0], 0, 0, 0);
        acc[1][1] = __builtin_amdgcn_mfma_f32_16x16x32_bf16(af1, bf1, acc[1][1], 0, 0, 0);
      }
    }
#pragma unroll
    for (int mt = 0; mt < 2; mt++)
#pragma unroll
      for (int r = 0; r < 4; r++) {
        int row = bm * 64 + wm * 32 + mt * 16 + quad * 4 + r;
#pragma unroll
        for (int nt = 0; nt < 2; nt++) {
          int col = bn * 64 + wn * 32 + nt * 16 + l16;
          A_QKV[(size_t)row * 1024 + col] = acc[mt][nt][r];
        }
      }
  }
  gsync(&bar[1], tid);

  // ======== S2: RoPE + V transpose ========
  for (int vb = bid; vb < 2560; vb += 1024) {
    if (vb < 2048) {
      int gid = vb * 256 + tid;
      int o = gid & 15;
      int t = (gid >> 4) & 2047;
      int h = (gid >> 15) & 7;
      int b = gid >> 18;
      const float* row = A_QKV + (size_t)(b * 2048 + t) * 1024;
      float freq = powf(10000.f, -(float)o / 16.f);
      float ang = (float)t * freq;
      float s, c;
      sincosf(ang, &s, &c);
      float g = qg[h] * 0.17677669529663687f;
      int qb = h * 32;
      float q0 = row[qb + o], q1 = row[qb + o + 16];
      float k0 = row[256 + qb + o], k1 = row[256 + qb + o + 16];
      u16* qo = A_Qb + ((size_t)((b * 8 + h) * 2048 + t)) * 32;
      u16* ko = A_Kb + ((size_t)((b * 8 + h) * 2048 + t)) * 32;
      qo[o] = f2b((q0 * c - q1 * s) * g);
      qo[o + 16] = f2b((q1 * c + q0 * s) * g);
      ko[o] = f2b(k0 * c - k1 * s);
      ko[o + 16] = f2b(k1 * c + k0 * s);
    } else {
      int idx = vb - 2048;
      const int tt = idx & 31, bh = idx >> 5;
      const int b = bh >> 3, h = bh & 7;
      u16 (*Ts)[72] = (u16(*)[72])SA;
      const int r = tid >> 2, q = tid & 3;
      const float* src = A_QKV + ((size_t)(b * 2048 + tt * 64 + r)) * 1024 + 512 + h * 64 + q * 16;
      __syncthreads();
#pragma unroll
      for (int j = 0; j < 4; j++) {
        float4 v = *(const float4*)(src + j * 4);
        Ts[q * 16 + j * 4 + 0][r] = f2b(v.x);
        Ts[q * 16 + j * 4 + 1][r] = f2b(v.y);
        Ts[q * 16 + j * 4 + 2][r] = f2b(v.z);
        Ts[q * 16 + j * 4 + 3][r] = f2b(v.w);
      }
      __syncthreads();
      u16* dst = A_Vt + ((size_t)(bh * 64 + r)) * 2048 + tt * 64 + q * 16;
      *(uint4*)dst = *(const uint4*)&Ts[r][q * 16];
      *(uint4*)(dst + 8) = *(const uint4*)&Ts[r][q * 16 + 8];
    }
  }
  gsync(&bar[2], tid);

  // ======== S3: attn split-K S=2, no-max softmax, prefetch ========
  {
    u16 (*Vts)[72] = (u16(*)[72])SA;
    u16 (*Ps)[72] = (u16(*)[72])SB;  // row = wave*16 + m
    const int bh = bid & 15;
    const int q0i = (bid >> 4) & 15;
    const int rem = bid >> 8;
    const int qt = (rem & 1) ? (31 - q0i) : q0i;
    const int s = rem >> 1;
    const int w = wave;
    const int mid = (qt + 1) >> 1;
    const int kt_beg = s ? mid : 0;
    const int kt_end = s ? (qt + 1) : mid;

    short8 qfrag = *(const short8*)(A_Qb + ((size_t)(bh * 2048 + qt * 64 + w * 16 + l16)) * 32 + quad * 8);
    floatx4 o_acc[4] = {};
    float l_part[4] = {0.f, 0.f, 0.f, 0.f};
    const u16* Kbase = A_Kb + (size_t)bh * 2048 * 32;
    const u16* Vtb = A_Vt + (size_t)bh * 64 * 2048;
    const int vr = tid >> 2, vc = (tid & 3) << 4;

    uint4 v0 = {}, v1 = {};
    short8 kf[4] = {};
    if (kt_beg < kt_end) {
      const u16* src = Vtb + (size_t)vr * 2048 + kt_beg * 64 + vc;
      v0 = *(const uint4*)src;
      v1 = *(const uint4*)(src + 8);
#pragma unroll
      for (int nt = 0; nt < 4; nt++)
        kf[nt] = *(const short8*)(Kbase + (size_t)(kt_beg * 64 + nt * 16 + l16) * 32 + quad * 8);
    }

    for (int kt = kt_beg; kt < kt_end; ++kt) {
      __syncthreads();
      *(uint4*)&Vts[vr][vc] = v0;
      *(uint4*)&Vts[vr][vc + 8] = v1;
      __syncthreads();
      const bool more = (kt + 1 < kt_end);
      uint4 v0n = {}, v1n = {};
      short8 kfn[4] = {};
      if (more) {
        const u16* src = Vtb + (size_t)vr * 2048 + (kt + 1) * 64 + vc;
        v0n = *(const uint4*)src;
        v1n = *(const uint4*)(src + 8);
#pragma unroll
        for (int nt = 0; nt < 4; nt++)
          kfn[nt] = *(const short8*)(Kbase + (size_t)((kt + 1) * 64 + nt * 16 + l16) * 32 + quad * 8);
      }

      floatx4 s_acc[4];
#pragma unroll
      for (int nt = 0; nt < 4; nt++) {
        floatx4 zz = {0.f, 0.f, 0.f, 0.f};
        s_acc[nt] = __builtin_amdgcn_mfma_f32_16x16x32_bf16(qfrag, kf[nt], zz, 0, 0, 0);
      }
      const bool diag = (kt == qt);
#pragma unroll
      for (int r = 0; r < 4; r++) {
        int mloc = w * 16 + quad * 4 + r;
        float psum = 0.f;
#pragma unroll
        for (int nt = 0; nt < 4; nt++) {
          float p = __expf(s_acc[nt][r]);
          if (diag && (nt * 16 + l16) > mloc) p = 0.f;
          psum += p;
          Ps[w * 16 + quad * 4 + r][nt * 16 + l16] = f2b(p);
        }
        l_part[r] += psum;
      }
#pragma unroll
      for (int kc = 0; kc < 2; kc++) {
        short8 pf = *(const short8*)&Ps[w * 16 + l16][kc * 32 + quad * 8];
#pragma unroll
        for (int nt = 0; nt < 4; nt++) {
          short8 vf = *(const short8*)&Vts[nt * 16 + l16][kc * 32 + quad * 8];
          o_acc[nt] = __builtin_amdgcn_mfma_f32_16x16x32_bf16(pf, vf, o_acc[nt], 0, 0, 0);
        }
      }
      v0 = v0n; v1 = v1n;
#pragma unroll
      for (int nt = 0; nt < 4; nt++) kf[nt] = kfn[nt];
    }

    const int pidx = (bh * 32 + qt) * 2 + s;
    float* pob = A_PO + (size_t)pidx * 4096;
#pragma unroll
    for (int r = 0; r < 4; r++) {
      float ls = l_part[r];
#pragma unroll
      for (int mk = 1; mk < 16; mk <<= 1) ls += __shfl_xor(ls, mk, 64);
      int row = w * 16 + quad * 4 + r;
#pragma unroll
      for (int nt = 0; nt < 4; nt++) pob[row * 64 + nt * 16 + l16] = o_acc[nt][r];
      if (l16 == 0) A_PL[pidx * 64 + row] = ls;
    }
  }
  gsync(&bar[3], tid);

  // ======== S4: combine + self-align (32 rows per block) ========
  for (int j = 0; j < 8; j++) {
    int ridx = bid * 32 + j * 4 + wave;
    int bh = ridx >> 11, tok = ridx & 2047;
    int qt = tok >> 6, row = tok & 63;
    int pidx = (bh * 32 + qt) * 2;
    const float* p0 = A_PO + (size_t)pidx * 4096 + row * 64;
    float o = p0[lane] + p0[4096 + lane];
    float l = A_PL[pidx * 64 + row] + A_PL[(pidx + 1) * 64 + row];
    float yv = o / l;
    int b = bh >> 3, h = bh & 7;
    float vv = A_QKV[(size_t)(b * 2048 + tok) * 1024 + 512 + h * 64 + lane];
    float ss = vv * vv, dot = yv * vv;
#pragma unroll
    for (int mk = 1; mk < 64; mk <<= 1) {
      ss += __shfl_xor(ss, mk, 64);
      dot += __shfl_xor(dot, mk, 64);
    }
    float coef = dot / fmaxf(ss, 1e-24f);
    A_Y2b[(size_t)(b * 2048 + tok) * 512 + h * 64 + lane] = f2b(yv - coef * vv);
  }
  gsync(&bar[4], tid);

  // ======== S5..S10: the 4 chain GEMMs (32x64 tile) + 2 LNs ========
  {
    u16 (*As)[72] = (u16(*)[72])SA;
    u16 (*Bs)[72] = (u16(*)[72])SB;
    const int bn = bid & 7, bm = bid >> 3;
    const int wm = wave >> 1, wn = wave & 1;
    const int ar = tid >> 3, ak = (tid & 7) << 3;
    const int br = tid >> 2, bk = (tid & 3) << 4;

#define GEMM32(Aptr, Bptr, Xptr, Cptr, Cbptr, EPI, DUAL)                                       \
    {                                                                                          \
      floatx4 acc[2] = {};                                                                     \
      const u16* Ap = (Aptr) + (size_t)(bm * 32 + ar) * 512 + ak;                              \
      const u16* Bp = (Bptr) + (size_t)(bn * 64 + br) * 512 + bk;                              \
      uint4 a0 = *(const uint4*)(Ap);                                                          \
      uint4 b0 = *(const uint4*)(Bp);                                                          \
      uint4 b1 = *(const uint4*)(Bp + 8);                                                      \
      for (int k0 = 0; k0 < 512; k0 += 64) {                                                   \
        __syncthreads();                                                                       \
        *(uint4*)&As[ar][ak] = a0;                                                             \
        *(uint4*)&Bs[br][bk] = b0;                                                             \
        *(uint4*)&Bs[br][bk + 8] = b1;                                                         \
        __syncthreads();                                                                       \
        if (k0 + 64 < 512) {                                                                   \
          a0 = *(const uint4*)(Ap + k0 + 64);                                                  \
          b0 = *(const uint4*)(Bp + k0 + 64);                                                  \
          b1 = *(const uint4*)(Bp + k0 + 72);                                                  \
        }                                                                                      \
        _Pragma("unroll")                                                                      \
        for (int kk = 0; kk < 2; kk++) {                                                       \
          short8 af = *(const short8*)&As[wm * 16 + l16][kk * 32 + quad * 8];                  \
          short8 bf0 = *(const short8*)&Bs[wn * 32 + l16][kk * 32 + quad * 8];                 \
          short8 bf1 = *(const short8*)&Bs[wn * 32 + 16 + l16][kk * 32 + quad * 8];            \
          acc[0] = __builtin_amdgcn_mfma_f32_16x16x32_bf16(af, bf0, acc[0], 0, 0, 0);          \
          acc[1] = __builtin_amdgcn_mfma_f32_16x16x32_bf16(af, bf1, acc[1], 0, 0, 0);          \
        }                                                                                      \
      }                                                                                        \
      _Pragma("unroll")                                                                        \
      for (int r = 0; r < 4; r++) {                                                            \
        int row = bm * 32 + wm * 16 + quad * 4 + r;                                            \
        _Pragma("unroll")                                                                      \
        for (int nt = 0; nt < 2; nt++) {                                                       \
          int col = bn * 64 + wn * 32 + nt * 16 + l16;                                         \
          float v = acc[nt][r];                                                                \
          if (EPI == 1) {                                                                      \
            v += (Xptr)[(size_t)row * 512 + col];                                              \
          } else if (EPI == 2) {                                                               \
            float xv = (Xptr)[(size_t)row * 512 + col];                                        \
            v = xv + v / (1.f + __expf(-v));                                                   \
          }                                                                                    \
          (Cptr)[(size_t)row * 512 + col] = v;                                                 \
          if (DUAL) (Cbptr)[(size_t)row * 512 + col] = f2b(v);                                 \
        }                                                                                      \
      }                                                                                        \
    }

#define LN_STAGE(inptr, gptr, bptr, outptr)                                                    \
    {                                                                                          \
      int row = bid * 4 + wave;                                                                \
      const float* rp = (inptr) + (size_t)row * 512 + lane * 8;                                \
      float4 aa = *(const float4*)rp;                                                          \
      float4 bb = *(const float4*)(rp + 4);                                                    \
      float v[8] = {aa.x, aa.y, aa.z, aa.w, bb.x, bb.y, bb.z, bb.w};                           \
      float s = 0.f;                                                                           \
      _Pragma("unroll") for (int e = 0; e < 8; e++) s += v[e];                                 \
      _Pragma("unroll") for (int mk = 1; mk < 64; mk <<= 1) s += __shfl_xor(s, mk, 64);        \
      float mean = s * (1.f / 512.f);                                                          \
      float vs = 0.f;                                                                          \
      _Pragma("unroll") for (int e = 0; e < 8; e++) { float d = v[e] - mean; vs = fmaf(d, d, vs); } \
      _Pragma("unroll") for (int mk = 1; mk < 64; mk <<= 1) vs += __shfl_xor(vs, mk, 64);      \
      float inv = rsqrtf(vs * (1.f / 512.f) + 1e-5f);                                          \
      int c0 = lane * 8;                                                                       \
      u16* op = (outptr) + (size_t)row * 512 + c0;                                             \
      ushort4 o1, o2;                                                                          \
      o1.x = f2b((v[0] - mean) * inv * (gptr)[c0 + 0] + (bptr)[c0 + 0]);                       \
      o1.y = f2b((v[1] - mean) * inv * (gptr)[c0 + 1] + (bptr)[c0 + 1]);                       \
      o1.z = f2b((v[2] - mean) * inv * (gptr)[c0 + 2] + (bptr)[c0 + 2]);                       \
      o1.w = f2b((v[3] - mean) * inv * (gptr)[c0 + 3] + (bptr)[c0 + 3]);                       \
      o2.x = f2b((v[4] - mean) * inv * (gptr)[c0 + 4] + (bptr)[c0 + 4]);                       \
      o2.y = f2b((v[5] - mean) * inv * (gptr)[c0 + 5] + (bptr)[c0 + 5]);                       \
      o2.z = f2b((v[6] - mean) * inv * (gptr)[c0 + 6] + (bptr)[c0 + 6]);                       \
      o2.w = f2b((v[7] - mean) * inv * (gptr)[c0 + 7] + (bptr)[c0 + 7]);                       \
      *(ushort4*)op = o1;                                                                      \
      *(ushort4*)(op + 4) = o2;                                                                \
    }

    GEMM32(A_Y2b, WPRb, x, A_H, A_Hb, 1, true);          // h = y2 @ wpr^T + x
    gsync(&bar[5], tid);
    GEMM32(A_Hb, W0b, x, A_QKV, A_Hb, 0, false);         // he0 = h @ w0^T
    gsync(&bar[6], tid);
    LN_STAGE(A_QKV, g1, b1, A_LNb);                      // ln1
    gsync(&bar[7], tid);
    GEMM32(A_LNb, W1b, A_H, A_Y, A_Hb, 2, false);        // he1 = h + silu(ln1 @ w1^T)
    gsync(&bar[8], tid);
    LN_STAGE(A_Y, g2, b2, A_LNb);                        // ln2
    gsync(&bar[9], tid);
    GEMM32(A_LNb, W2b, A_Y, A_HE2, A_Hb, 2, false);      // he2 = he1 + silu(ln2 @ w2^T)
    gsync(&bar[10], tid);
  }

  // ======== S11: RMS + 512->32 projection + softplus/tanh ========
  if (bid < 512) {
    int tok = bid * 8 + (tid >> 5);
    int n = tid & 31;
    const float* rr = A_HE2 + (size_t)tok * 512;
    float ss = 0.f;
#pragma unroll
    for (int j = 0; j < 4; j++) {
      float4 v = ((const float4*)rr)[j * 32 + n];
      ss = fmaf(v.x, v.x, fmaf(v.y, v.y, fmaf(v.z, v.z, fmaf(v.w, v.w, ss))));
    }
#pragma unroll
    for (int mk = 1; mk < 32; mk <<= 1) ss += __shfl_xor(ss, mk, 64);
    float rinv = rsqrtf(ss * (1.f / 512.f) + 1e-6f);
    const float* w = wout + (size_t)n * 512;
    float acc = 0.f;
    for (int d = 0; d < 512; d += 4) {
      float4 rv = *(const float4*)(rr + d);
      float4 wv = *(const float4*)(w + d);
      acc = fmaf(rv.x, wv.x, acc);
      acc = fmaf(rv.y, wv.y, acc);
      acc = fmaf(rv.z, wv.z, acc);
      acc = fmaf(rv.w, wv.w, acc);
    }
    float c = ct[n];
    float sp = (c > 20.f) ? c : log1pf(__expf(c));
    z[(size_t)tok * 32 + n] = tanhf(acc * rinv / (sp + 1e-4f));
  }
}

extern "C" void kernel_launch(void* const* d_in, const int* in_sizes, int n_in,
                              void* d_out, int out_size, void* d_ws, size_t ws_size,
                              hipStream_t stream) {
  const float* x = (const float*)d_in[0];
  const float* qp = (const float*)d_in[1];
  const float* kp = (const float*)d_in[2];
  const float* wv = (const float*)d_in[3];
  const float* wpr = (const float*)d_in[4];
  const float* qg = (const float*)d_in[5];
  const float* w0 = (const float*)d_in[6];
  const float* g1 = (const float*)d_in[7];
  const float* b1 = (const float*)d_in[8];
  const float* w1 = (const float*)d_in[9];
  const float* g2 = (const float*)d_in[10];
  const float* b2 = (const float*)d_in[11];
  const float* w2 = (const float*)d_in[12];
  const float* wout = (const float*)d_in[13];
  const float* ct = (const float*)d_in[14];
  float* z = (float*)d_out;
  float* ws = (float*)d_ws;

  unsigned* bar = (unsigned*)(ws + 30 * 1024 * 1024);  // far from all live buffers
  hipMemsetAsync(bar, 0, 64, stream);
  hipLaunchKernelGGL(mega, dim3(1024), dim3(256), 0, stream,
                     x, qp, kp, wv, wpr, qg, w0, g1, b1, w1, g2, b2, w2, wout, ct, z, ws, bar);
}

// Round 12
// 2544.278 us; speedup vs baseline: 1.1227x; 1.1227x over previous
//
#include <hip/hip_runtime.h>
#include <math.h>

typedef unsigned short u16;
typedef __attribute__((ext_vector_type(8))) short short8;
typedef __attribute__((ext_vector_type(4))) float floatx4;

__device__ __forceinline__ u16 f2b(float f) {
  unsigned u = __float_as_uint(f);
  return (u16)((u + 0x7fffu + ((u >> 16) & 1u)) >> 16);
}

#define NBLK 1024u

// two-line sense barrier: arrival counter at slot+0, release flag at slot+32 (separate 128B line).
// slots are 64 uints (256B) apart; all pre-zeroed by hipMemsetAsync before launch.
__device__ __forceinline__ void gsync(unsigned* bar, int idx, int tid) {
  __syncthreads();
  __threadfence();
  if (tid == 0) {
    unsigned* cnt = bar + idx * 64;
    unsigned* rel = bar + idx * 64 + 32;
    unsigned old = __hip_atomic_fetch_add(cnt, 1u, __ATOMIC_ACQ_REL, __HIP_MEMORY_SCOPE_AGENT);
    if (old == NBLK - 1u) {
      __hip_atomic_store(rel, 1u, __ATOMIC_RELEASE, __HIP_MEMORY_SCOPE_AGENT);
    } else {
      while (!__hip_atomic_load(rel, __ATOMIC_ACQUIRE, __HIP_MEMORY_SCOPE_AGENT))
        __builtin_amdgcn_s_sleep(8);
    }
  }
  __syncthreads();
  __threadfence();
}

__global__ __launch_bounds__(256, 4) void mega(
    const float* __restrict__ x, const float* __restrict__ qp, const float* __restrict__ kp,
    const float* __restrict__ wv, const float* __restrict__ wpr, const float* __restrict__ qg,
    const float* __restrict__ w0, const float* __restrict__ g1, const float* __restrict__ b1,
    const float* __restrict__ w1, const float* __restrict__ g2, const float* __restrict__ b2,
    const float* __restrict__ w2, const float* __restrict__ wout, const float* __restrict__ ct,
    float* __restrict__ z, float* __restrict__ ws, unsigned* __restrict__ bar) {
  const int bid = blockIdx.x, tid = threadIdx.x;
  const int lane = tid & 63, wave = tid >> 6;
  const int quad = lane >> 4, l16 = lane & 15;

  const size_t MEG = 1024 * 1024;
  float* A_QKV = ws;                          // [0..4M) qkv fp32; later he0 [0..2M)
  u16* A_Qb = (u16*)(ws + 4 * MEG);
  u16* A_Kb = (u16*)(ws + 4 * MEG + 524288);
  u16* A_Vt = (u16*)(ws + 5 * MEG);
  float* A_HE2 = ws + 4 * MEG;                // alias after attention
  float* A_PO = ws + 6 * MEG;                 // [6M..10M) partial O
  float* A_Y = ws + 6 * MEG;                  // later he1 [6M..8M)
  float* A_H = ws + 8 * MEG;                  // later h [8M..10M)
  u16* A_Y2b = (u16*)(ws + 10 * MEG);
  u16* A_Hb = (u16*)(ws + 11 * MEG);
  u16* A_LNb = (u16*)(ws + 12 * MEG);
  u16* XB = (u16*)(ws + 13 * MEG);
  float* A_PL = ws + 13 * MEG;                // aliases XB (dead after S1); written in S3
  u16* WCATb = (u16*)(ws + 14 * MEG);
  u16* WPRb = WCATb + 524288;
  u16* W0b = WPRb + 262144;
  u16* W1b = W0b + 262144;
  u16* W2b = W1b + 262144;

  __shared__ __align__(16) u16 SA[4608];  // 64*72
  __shared__ __align__(16) u16 SB[4608];

  // ======== S0: casts (x->bf16, 4 weights, Wcat) ========
  for (int vb = bid; vb < 5120; vb += 1024) {
    if (vb < 2048) {
      int i = vb * 256 + tid;
      float4 v = ((const float4*)x)[i];
      ushort4 o; o.x = f2b(v.x); o.y = f2b(v.y); o.z = f2b(v.z); o.w = f2b(v.w);
      ((ushort4*)XB)[i] = o;
    } else if (vb < 3072) {
      int i = (vb - 2048) * 256 + tid;
      int sel = i >> 16, j = i & 65535;
      const float* s = sel == 0 ? wpr : sel == 1 ? w0 : sel == 2 ? w1 : w2;
      u16* d = sel == 0 ? WPRb : sel == 1 ? W0b : sel == 2 ? W1b : W2b;
      float4 v = ((const float4*)s)[j];
      ushort4 o; o.x = f2b(v.x); o.y = f2b(v.y); o.z = f2b(v.z); o.w = f2b(v.w);
      ((ushort4*)d)[j] = o;
    } else {
      int i = (vb - 3072) * 256 + tid;
      int d = i & 511, c = i >> 9;
      float v;
      if (c < 512) {
        int hh = c >> 5, o = c & 31;
        const float* src = (hh < 8) ? qp : kp;
        int h = hh & 7;
        v = src[(h * 512 + d) * 32 + o];
      } else {
        v = wv[(c - 512) * 512 + d];
      }
      WCATb[i] = f2b(v);
    }
  }
  gsync(bar, 0, tid);

  // ======== S1: QKV GEMM 64x64 (bid -> bn 0..15, bm 0..63), C = A_QKV (N=1024) ========
  {
    u16 (*As)[72] = (u16(*)[72])SA;
    u16 (*Bs)[72] = (u16(*)[72])SB;
    const int bn = bid & 15, bm = bid >> 4;
    const int wm = wave >> 1, wn = wave & 1;
    const int sr = tid >> 2, sk = (tid & 3) << 4;
    floatx4 acc[2][2] = {};
    const u16* Ap = XB + (size_t)(bm * 64 + sr) * 512 + sk;
    const u16* Bp = WCATb + (size_t)(bn * 64 + sr) * 512 + sk;
    uint4 a0 = *(const uint4*)(Ap);
    uint4 a1 = *(const uint4*)(Ap + 8);
    uint4 b0 = *(const uint4*)(Bp);
    uint4 b1 = *(const uint4*)(Bp + 8);
    for (int k0 = 0; k0 < 512; k0 += 64) {
      __syncthreads();
      *(uint4*)&As[sr][sk] = a0;
      *(uint4*)&As[sr][sk + 8] = a1;
      *(uint4*)&Bs[sr][sk] = b0;
      *(uint4*)&Bs[sr][sk + 8] = b1;
      __syncthreads();
      if (k0 + 64 < 512) {
        a0 = *(const uint4*)(Ap + k0 + 64);
        a1 = *(const uint4*)(Ap + k0 + 72);
        b0 = *(const uint4*)(Bp + k0 + 64);
        b1 = *(const uint4*)(Bp + k0 + 72);
      }
#pragma unroll
      for (int kk = 0; kk < 2; kk++) {
        short8 af0 = *(const short8*)&As[wm * 32 + l16][kk * 32 + quad * 8];
        short8 af1 = *(const short8*)&As[wm * 32 + 16 + l16][kk * 32 + quad * 8];
        short8 bf0 = *(const short8*)&Bs[wn * 32 + l16][kk * 32 + quad * 8];
        short8 bf1 = *(const short8*)&Bs[wn * 32 + 16 + l16][kk * 32 + quad * 8];
        acc[0][0] = __builtin_amdgcn_mfma_f32_16x16x32_bf16(af0, bf0, acc[0][0], 0, 0, 0);
        acc[0][1] = __builtin_amdgcn_mfma_f32_16x16x32_bf16(af0, bf1, acc[0][1], 0, 0, 0);
        acc[1][0] = __builtin_amdgcn_mfma_f32_16x16x32_bf16(af1, bf0, acc[1][0], 0, 0, 0);
        acc[1][1] = __builtin_amdgcn_mfma_f32_16x16x32_bf16(af1, bf1, acc[1][1], 0, 0, 0);
      }
    }
#pragma unroll
    for (int mt = 0; mt < 2; mt++)
#pragma unroll
      for (int r = 0; r < 4; r++) {
        int row = bm * 64 + wm * 32 + mt * 16 + quad * 4 + r;
#pragma unroll
        for (int nt = 0; nt < 2; nt++) {
          int col = bn * 64 + wn * 32 + nt * 16 + l16;
          A_QKV[(size_t)row * 1024 + col] = acc[mt][nt][r];
        }
      }
  }
  gsync(bar, 1, tid);

  // ======== S2: RoPE + V transpose ========
  for (int vb = bid; vb < 2560; vb += 1024) {
    if (vb < 2048) {
      int gid = vb * 256 + tid;
      int o = gid & 15;
      int t = (gid >> 4) & 2047;
      int h = (gid >> 15) & 7;
      int b = gid >> 18;
      const float* row = A_QKV + (size_t)(b * 2048 + t) * 1024;
      float freq = powf(10000.f, -(float)o / 16.f);
      float ang = (float)t * freq;
      float s, c;
      sincosf(ang, &s, &c);
      float g = qg[h] * 0.17677669529663687f;
      int qb = h * 32;
      float q0 = row[qb + o], q1 = row[qb + o + 16];
      float k0 = row[256 + qb + o], k1 = row[256 + qb + o + 16];
      u16* qo = A_Qb + ((size_t)((b * 8 + h) * 2048 + t)) * 32;
      u16* ko = A_Kb + ((size_t)((b * 8 + h) * 2048 + t)) * 32;
      qo[o] = f2b((q0 * c - q1 * s) * g);
      qo[o + 16] = f2b((q1 * c + q0 * s) * g);
      ko[o] = f2b(k0 * c - k1 * s);
      ko[o + 16] = f2b(k1 * c + k0 * s);
    } else {
      int idx = vb - 2048;
      const int tt = idx & 31, bh = idx >> 5;
      const int b = bh >> 3, h = bh & 7;
      u16 (*Ts)[72] = (u16(*)[72])SA;
      const int r = tid >> 2, q = tid & 3;
      const float* src = A_QKV + ((size_t)(b * 2048 + tt * 64 + r)) * 1024 + 512 + h * 64 + q * 16;
      __syncthreads();
#pragma unroll
      for (int j = 0; j < 4; j++) {
        float4 v = *(const float4*)(src + j * 4);
        Ts[q * 16 + j * 4 + 0][r] = f2b(v.x);
        Ts[q * 16 + j * 4 + 1][r] = f2b(v.y);
        Ts[q * 16 + j * 4 + 2][r] = f2b(v.z);
        Ts[q * 16 + j * 4 + 3][r] = f2b(v.w);
      }
      __syncthreads();
      u16* dst = A_Vt + ((size_t)(bh * 64 + r)) * 2048 + tt * 64 + q * 16;
      *(uint4*)dst = *(const uint4*)&Ts[r][q * 16];
      *(uint4*)(dst + 8) = *(const uint4*)&Ts[r][q * 16 + 8];
    }
  }
  gsync(bar, 2, tid);

  // ======== S3: attn split-K S=2, no-max softmax, prefetch ========
  {
    u16 (*Vts)[72] = (u16(*)[72])SA;
    u16 (*Ps)[72] = (u16(*)[72])SB;  // row = wave*16 + m
    const int bh = bid & 15;
    const int q0i = (bid >> 4) & 15;
    const int rem = bid >> 8;
    const int qt = (rem & 1) ? (31 - q0i) : q0i;
    const int s = rem >> 1;
    const int w = wave;
    const int mid = (qt + 1) >> 1;
    const int kt_beg = s ? mid : 0;
    const int kt_end = s ? (qt + 1) : mid;

    short8 qfrag = *(const short8*)(A_Qb + ((size_t)(bh * 2048 + qt * 64 + w * 16 + l16)) * 32 + quad * 8);
    floatx4 o_acc[4] = {};
    float l_part[4] = {0.f, 0.f, 0.f, 0.f};
    const u16* Kbase = A_Kb + (size_t)bh * 2048 * 32;
    const u16* Vtb = A_Vt + (size_t)bh * 64 * 2048;
    const int vr = tid >> 2, vc = (tid & 3) << 4;

    uint4 v0 = {}, v1 = {};
    short8 kf[4] = {};
    if (kt_beg < kt_end) {
      const u16* src = Vtb + (size_t)vr * 2048 + kt_beg * 64 + vc;
      v0 = *(const uint4*)src;
      v1 = *(const uint4*)(src + 8);
#pragma unroll
      for (int nt = 0; nt < 4; nt++)
        kf[nt] = *(const short8*)(Kbase + (size_t)(kt_beg * 64 + nt * 16 + l16) * 32 + quad * 8);
    }

    for (int kt = kt_beg; kt < kt_end; ++kt) {
      __syncthreads();
      *(uint4*)&Vts[vr][vc] = v0;
      *(uint4*)&Vts[vr][vc + 8] = v1;
      __syncthreads();
      const bool more = (kt + 1 < kt_end);
      uint4 v0n = {}, v1n = {};
      short8 kfn[4] = {};
      if (more) {
        const u16* src = Vtb + (size_t)vr * 2048 + (kt + 1) * 64 + vc;
        v0n = *(const uint4*)src;
        v1n = *(const uint4*)(src + 8);
#pragma unroll
        for (int nt = 0; nt < 4; nt++)
          kfn[nt] = *(const short8*)(Kbase + (size_t)((kt + 1) * 64 + nt * 16 + l16) * 32 + quad * 8);
      }

      floatx4 s_acc[4];
#pragma unroll
      for (int nt = 0; nt < 4; nt++) {
        floatx4 zz = {0.f, 0.f, 0.f, 0.f};
        s_acc[nt] = __builtin_amdgcn_mfma_f32_16x16x32_bf16(qfrag, kf[nt], zz, 0, 0, 0);
      }
      const bool diag = (kt == qt);
#pragma unroll
      for (int r = 0; r < 4; r++) {
        int mloc = w * 16 + quad * 4 + r;
        float psum = 0.f;
#pragma unroll
        for (int nt = 0; nt < 4; nt++) {
          float p = __expf(s_acc[nt][r]);
          if (diag && (nt * 16 + l16) > mloc) p = 0.f;
          psum += p;
          Ps[w * 16 + quad * 4 + r][nt * 16 + l16] = f2b(p);
        }
        l_part[r] += psum;
      }
#pragma unroll
      for (int kc = 0; kc < 2; kc++) {
        short8 pf = *(const short8*)&Ps[w * 16 + l16][kc * 32 + quad * 8];
#pragma unroll
        for (int nt = 0; nt < 4; nt++) {
          short8 vf = *(const short8*)&Vts[nt * 16 + l16][kc * 32 + quad * 8];
          o_acc[nt] = __builtin_amdgcn_mfma_f32_16x16x32_bf16(pf, vf, o_acc[nt], 0, 0, 0);
        }
      }
      v0 = v0n; v1 = v1n;
#pragma unroll
      for (int nt = 0; nt < 4; nt++) kf[nt] = kfn[nt];
    }

    const int pidx = (bh * 32 + qt) * 2 + s;
    float* pob = A_PO + (size_t)pidx * 4096;
#pragma unroll
    for (int r = 0; r < 4; r++) {
      float ls = l_part[r];
#pragma unroll
      for (int mk = 1; mk < 16; mk <<= 1) ls += __shfl_xor(ls, mk, 64);
      int row = w * 16 + quad * 4 + r;
#pragma unroll
      for (int nt = 0; nt < 4; nt++) pob[row * 64 + nt * 16 + l16] = o_acc[nt][r];
      if (l16 == 0) A_PL[pidx * 64 + row] = ls;
    }
  }
  gsync(bar, 3, tid);

  // ======== S4: combine + self-align (32 rows per block) ========
  for (int j = 0; j < 8; j++) {
    int ridx = bid * 32 + j * 4 + wave;
    int bh = ridx >> 11, tok = ridx & 2047;
    int qt = tok >> 6, row = tok & 63;
    int pidx = (bh * 32 + qt) * 2;
    const float* p0 = A_PO + (size_t)pidx * 4096 + row * 64;
    float o = p0[lane] + p0[4096 + lane];
    float l = A_PL[pidx * 64 + row] + A_PL[(pidx + 1) * 64 + row];
    float yv = o / l;
    int b = bh >> 3, h = bh & 7;
    float vv = A_QKV[(size_t)(b * 2048 + tok) * 1024 + 512 + h * 64 + lane];
    float ss = vv * vv, dot = yv * vv;
#pragma unroll
    for (int mk = 1; mk < 64; mk <<= 1) {
      ss += __shfl_xor(ss, mk, 64);
      dot += __shfl_xor(dot, mk, 64);
    }
    float coef = dot / fmaxf(ss, 1e-24f);
    A_Y2b[(size_t)(b * 2048 + tok) * 512 + h * 64 + lane] = f2b(yv - coef * vv);
  }
  gsync(bar, 4, tid);

  // ======== S5..S10: the 4 chain GEMMs (32x64 tile) + 2 LNs ========
  {
    u16 (*As)[72] = (u16(*)[72])SA;
    u16 (*Bs)[72] = (u16(*)[72])SB;
    const int bn = bid & 7, bm = bid >> 3;
    const int wm = wave >> 1, wn = wave & 1;
    const int ar = tid >> 3, ak = (tid & 7) << 3;
    const int br = tid >> 2, bk = (tid & 3) << 4;

#define GEMM32(Aptr, Bptr, Xptr, Cptr, Cbptr, EPI, DUAL)                                       \
    {                                                                                          \
      floatx4 acc[2] = {};                                                                     \
      const u16* Ap = (Aptr) + (size_t)(bm * 32 + ar) * 512 + ak;                              \
      const u16* Bp = (Bptr) + (size_t)(bn * 64 + br) * 512 + bk;                              \
      uint4 a0 = *(const uint4*)(Ap);                                                          \
      uint4 b0 = *(const uint4*)(Bp);                                                          \
      uint4 b1 = *(const uint4*)(Bp + 8);                                                      \
      for (int k0 = 0; k0 < 512; k0 += 64) {                                                   \
        __syncthreads();                                                                       \
        *(uint4*)&As[ar][ak] = a0;                                                             \
        *(uint4*)&Bs[br][bk] = b0;                                                             \
        *(uint4*)&Bs[br][bk + 8] = b1;                                                         \
        __syncthreads();                                                                       \
        if (k0 + 64 < 512) {                                                                   \
          a0 = *(const uint4*)(Ap + k0 + 64);                                                  \
          b0 = *(const uint4*)(Bp + k0 + 64);                                                  \
          b1 = *(const uint4*)(Bp + k0 + 72);                                                  \
        }                                                                                      \
        _Pragma("unroll")                                                                      \
        for (int kk = 0; kk < 2; kk++) {                                                       \
          short8 af = *(const short8*)&As[wm * 16 + l16][kk * 32 + quad * 8];                  \
          short8 bf0 = *(const short8*)&Bs[wn * 32 + l16][kk * 32 + quad * 8];                 \
          short8 bf1 = *(const short8*)&Bs[wn * 32 + 16 + l16][kk * 32 + quad * 8];            \
          acc[0] = __builtin_amdgcn_mfma_f32_16x16x32_bf16(af, bf0, acc[0], 0, 0, 0);          \
          acc[1] = __builtin_amdgcn_mfma_f32_16x16x32_bf16(af, bf1, acc[1], 0, 0, 0);          \
        }                                                                                      \
      }                                                                                        \
      _Pragma("unroll")                                                                        \
      for (int r = 0; r < 4; r++) {                                                            \
        int row = bm * 32 + wm * 16 + quad * 4 + r;                                            \
        _Pragma("unroll")                                                                      \
        for (int nt = 0; nt < 2; nt++) {                                                       \
          int col = bn * 64 + wn * 32 + nt * 16 + l16;                                         \
          float v = acc[nt][r];                                                                \
          if (EPI == 1) {                                                                      \
            v += (Xptr)[(size_t)row * 512 + col];                                              \
          } else if (EPI == 2) {                                                               \
            float xv = (Xptr)[(size_t)row * 512 + col];                                        \
            v = xv + v / (1.f + __expf(-v));                                                   \
          }                                                                                    \
          (Cptr)[(size_t)row * 512 + col] = v;                                                 \
          if (DUAL) (Cbptr)[(size_t)row * 512 + col] = f2b(v);                                 \
        }                                                                                      \
      }                                                                                        \
    }

#define LN_STAGE(inptr, gptr, bptr, outptr)                                                    \
    {                                                                                          \
      int row = bid * 4 + wave;                                                                \
      const float* rp = (inptr) + (size_t)row * 512 + lane * 8;                                \
      float4 aa = *(const float4*)rp;                                                          \
      float4 bb = *(const float4*)(rp + 4);                                                    \
      float v[8] = {aa.x, aa.y, aa.z, aa.w, bb.x, bb.y, bb.z, bb.w};                           \
      float s = 0.f;                                                                           \
      _Pragma("unroll") for (int e = 0; e < 8; e++) s += v[e];                                 \
      _Pragma("unroll") for (int mk = 1; mk < 64; mk <<= 1) s += __shfl_xor(s, mk, 64);        \
      float mean = s * (1.f / 512.f);                                                          \
      float vs = 0.f;                                                                          \
      _Pragma("unroll") for (int e = 0; e < 8; e++) { float d = v[e] - mean; vs = fmaf(d, d, vs); } \
      _Pragma("unroll") for (int mk = 1; mk < 64; mk <<= 1) vs += __shfl_xor(vs, mk, 64);      \
      float inv = rsqrtf(vs * (1.f / 512.f) + 1e-5f);                                          \
      int c0 = lane * 8;                                                                       \
      u16* op = (outptr) + (size_t)row * 512 + c0;                                             \
      ushort4 o1, o2;                                                                          \
      o1.x = f2b((v[0] - mean) * inv * (gptr)[c0 + 0] + (bptr)[c0 + 0]);                       \
      o1.y = f2b((v[1] - mean) * inv * (gptr)[c0 + 1] + (bptr)[c0 + 1]);                       \
      o1.z = f2b((v[2] - mean) * inv * (gptr)[c0 + 2] + (bptr)[c0 + 2]);                       \
      o1.w = f2b((v[3] - mean) * inv * (gptr)[c0 + 3] + (bptr)[c0 + 3]);                       \
      o2.x = f2b((v[4] - mean) * inv * (gptr)[c0 + 4] + (bptr)[c0 + 4]);                       \
      o2.y = f2b((v[5] - mean) * inv * (gptr)[c0 + 5] + (bptr)[c0 + 5]);                       \
      o2.z = f2b((v[6] - mean) * inv * (gptr)[c0 + 6] + (bptr)[c0 + 6]);                       \
      o2.w = f2b((v[7] - mean) * inv * (gptr)[c0 + 7] + (bptr)[c0 + 7]);                       \
      *(ushort4*)op = o1;                                                                      \
      *(ushort4*)(op + 4) = o2;                                                                \
    }

    GEMM32(A_Y2b, WPRb, x, A_H, A_Hb, 1, true);          // h = y2 @ wpr^T + x
    gsync(bar, 5, tid);
    GEMM32(A_Hb, W0b, x, A_QKV, A_Hb, 0, false);         // he0 = h @ w0^T
    gsync(bar, 6, tid);
    LN_STAGE(A_QKV, g1, b1, A_LNb);                      // ln1
    gsync(bar, 7, tid);
    GEMM32(A_LNb, W1b, A_H, A_Y, A_Hb, 2, false);        // he1 = h + silu(ln1 @ w1^T)
    gsync(bar, 8, tid);
    LN_STAGE(A_Y, g2, b2, A_LNb);                        // ln2
    gsync(bar, 9, tid);
    GEMM32(A_LNb, W2b, A_Y, A_HE2, A_Hb, 2, false);      // he2 = he1 + silu(ln2 @ w2^T)
    gsync(bar, 10, tid);
  }

  // ======== S11: RMS + 512->32 projection + softplus/tanh ========
  if (bid < 512) {
    int tok = bid * 8 + (tid >> 5);
    int n = tid & 31;
    const float* rr = A_HE2 + (size_t)tok * 512;
    float ss = 0.f;
#pragma unroll
    for (int j = 0; j < 4; j++) {
      float4 v = ((const float4*)rr)[j * 32 + n];
      ss = fmaf(v.x, v.x, fmaf(v.y, v.y, fmaf(v.z, v.z, fmaf(v.w, v.w, ss))));
    }
#pragma unroll
    for (int mk = 1; mk < 32; mk <<= 1) ss += __shfl_xor(ss, mk, 64);
    float rinv = rsqrtf(ss * (1.f / 512.f) + 1e-6f);
    const float* w = wout + (size_t)n * 512;
    float acc = 0.f;
    for (int d = 0; d < 512; d += 4) {
      float4 rv = *(const float4*)(rr + d);
      float4 wv = *(const float4*)(w + d);
      acc = fmaf(rv.x, wv.x, acc);
      acc = fmaf(rv.y, wv.y, acc);
      acc = fmaf(rv.z, wv.z, acc);
      acc = fmaf(rv.w, wv.w, acc);
    }
    float c = ct[n];
    float sp = (c > 20.f) ? c : log1pf(__expf(c));
    z[(size_t)tok * 32 + n] = tanhf(acc * rinv / (sp + 1e-4f));
  }
}

extern "C" void kernel_launch(void* const* d_in, const int* in_sizes, int n_in,
                              void* d_out, int out_size, void* d_ws, size_t ws_size,
                              hipStream_t stream) {
  const float* x = (const float*)d_in[0];
  const float* qp = (const float*)d_in[1];
  const float* kp = (const float*)d_in[2];
  const float* wv = (const float*)d_in[3];
  const float* wpr = (const float*)d_in[4];
  const float* qg = (const float*)d_in[5];
  const float* w0 = (const float*)d_in[6];
  const float* g1 = (const float*)d_in[7];
  const float* b1 = (const float*)d_in[8];
  const float* w1 = (const float*)d_in[9];
  const float* g2 = (const float*)d_in[10];
  const float* b2 = (const float*)d_in[11];
  const float* w2 = (const float*)d_in[12];
  const float* wout = (const float*)d_in[13];
  const float* ct = (const float*)d_in[14];
  float* z = (float*)d_out;
  float* ws = (float*)d_ws;

  unsigned* bar = (unsigned*)(ws + 30 * 1024 * 1024);  // far from all live buffers
  hipMemsetAsync(bar, 0, 4096, stream);
  hipLaunchKernelGGL(mega, dim3(1024), dim3(256), 0, stream,
                     x, qp, kp, wv, wpr, qg, w0, g1, b1, w1, g2, b2, w2, wout, ct, z, ws, bar);
}

// Round 13
// 2456.246 us; speedup vs baseline: 1.1630x; 1.0358x over previous
//
#include <hip/hip_runtime.h>
#include <math.h>

typedef unsigned short u16;
typedef __attribute__((ext_vector_type(8))) short short8;
typedef __attribute__((ext_vector_type(4))) float floatx4;

__device__ __forceinline__ u16 f2b(float f) {
  unsigned u = __float_as_uint(f);
  return (u16)((u + 0x7fffu + ((u >> 16) & 1u)) >> 16);
}

#define NBLK 1024

// Store-based grid barrier: no atomic RMW anywhere.
// flags[0..1023]: per-block arrival tokens (monotonic). rel[idx*32]: per-barrier release token.
// Block 0 detects arrival (each thread polls 4 flags), publishes release; others spin on release.
__device__ __forceinline__ void gsync(unsigned* flags, unsigned* rel, int idx, int bid, int tid) {
  const unsigned tok = (unsigned)idx + 1u;
  __syncthreads();
  __threadfence();
  if (bid == 0) {
    if (tid == 0) __hip_atomic_store(&flags[0], tok, __ATOMIC_RELAXED, __HIP_MEMORY_SCOPE_AGENT);
#pragma unroll
    for (int j = 0; j < 4; j++) {
      int b = tid + j * 256;
      while (__hip_atomic_load(&flags[b], __ATOMIC_RELAXED, __HIP_MEMORY_SCOPE_AGENT) < tok)
        __builtin_amdgcn_s_sleep(1);
    }
    __syncthreads();
    if (tid == 0) __hip_atomic_store(&rel[idx * 32], tok, __ATOMIC_RELEASE, __HIP_MEMORY_SCOPE_AGENT);
  } else {
    if (tid == 0) {
      __hip_atomic_store(&flags[bid], tok, __ATOMIC_RELAXED, __HIP_MEMORY_SCOPE_AGENT);
      while (__hip_atomic_load(&rel[idx * 32], __ATOMIC_ACQUIRE, __HIP_MEMORY_SCOPE_AGENT) < tok)
        __builtin_amdgcn_s_sleep(8);
    }
    __syncthreads();
  }
  __threadfence();
}

__global__ __launch_bounds__(256, 4) void mega(
    const float* __restrict__ x, const float* __restrict__ qp, const float* __restrict__ kp,
    const float* __restrict__ wv, const float* __restrict__ wpr, const float* __restrict__ qg,
    const float* __restrict__ w0, const float* __restrict__ g1, const float* __restrict__ b1,
    const float* __restrict__ w1, const float* __restrict__ g2, const float* __restrict__ b2,
    const float* __restrict__ w2, const float* __restrict__ wout, const float* __restrict__ ct,
    float* __restrict__ z, float* __restrict__ ws, unsigned* __restrict__ flags,
    unsigned* __restrict__ rel) {
  const int bid = blockIdx.x, tid = threadIdx.x;
  const int lane = tid & 63, wave = tid >> 6;
  const int quad = lane >> 4, l16 = lane & 15;

  const size_t MEG = 1024 * 1024;
  float* A_QKV = ws;                          // [0..4M) qkv fp32; later he0 [0..2M)
  u16* A_Qb = (u16*)(ws + 4 * MEG);
  u16* A_Kb = (u16*)(ws + 4 * MEG + 524288);
  u16* A_Vt = (u16*)(ws + 5 * MEG);
  float* A_HE2 = ws + 4 * MEG;                // alias after attention
  float* A_PO = ws + 6 * MEG;                 // [6M..10M) partial O
  float* A_Y = ws + 6 * MEG;                  // later he1 [6M..8M)
  float* A_H = ws + 8 * MEG;                  // later h [8M..10M)
  u16* A_Y2b = (u16*)(ws + 10 * MEG);
  u16* A_Hb = (u16*)(ws + 11 * MEG);
  u16* A_LNb = (u16*)(ws + 12 * MEG);
  u16* XB = (u16*)(ws + 13 * MEG);
  float* A_PL = ws + 13 * MEG;                // aliases XB (dead after S1); written in S3
  u16* WCATb = (u16*)(ws + 14 * MEG);
  u16* WPRb = WCATb + 524288;
  u16* W0b = WPRb + 262144;
  u16* W1b = W0b + 262144;
  u16* W2b = W1b + 262144;

  __shared__ __align__(16) u16 SA[4608];  // 64*72
  __shared__ __align__(16) u16 SB[4608];

  // ======== S0: casts (x->bf16, 4 weights, Wcat) ========
  for (int vb = bid; vb < 5120; vb += 1024) {
    if (vb < 2048) {
      int i = vb * 256 + tid;
      float4 v = ((const float4*)x)[i];
      ushort4 o; o.x = f2b(v.x); o.y = f2b(v.y); o.z = f2b(v.z); o.w = f2b(v.w);
      ((ushort4*)XB)[i] = o;
    } else if (vb < 3072) {
      int i = (vb - 2048) * 256 + tid;
      int sel = i >> 16, j = i & 65535;
      const float* s = sel == 0 ? wpr : sel == 1 ? w0 : sel == 2 ? w1 : w2;
      u16* d = sel == 0 ? WPRb : sel == 1 ? W0b : sel == 2 ? W1b : W2b;
      float4 v = ((const float4*)s)[j];
      ushort4 o; o.x = f2b(v.x); o.y = f2b(v.y); o.z = f2b(v.z); o.w = f2b(v.w);
      ((ushort4*)d)[j] = o;
    } else {
      int i = (vb - 3072) * 256 + tid;
      int d = i & 511, c = i >> 9;
      float v;
      if (c < 512) {
        int hh = c >> 5, o = c & 31;
        const float* src = (hh < 8) ? qp : kp;
        int h = hh & 7;
        v = src[(h * 512 + d) * 32 + o];
      } else {
        v = wv[(c - 512) * 512 + d];
      }
      WCATb[i] = f2b(v);
    }
  }
  gsync(flags, rel, 0, bid, tid);

  // ======== S1: QKV GEMM 64x64 (bid -> bn 0..15, bm 0..63), C = A_QKV (N=1024) ========
  {
    u16 (*As)[72] = (u16(*)[72])SA;
    u16 (*Bs)[72] = (u16(*)[72])SB;
    const int bn = bid & 15, bm = bid >> 4;
    const int wm = wave >> 1, wn = wave & 1;
    const int sr = tid >> 2, sk = (tid & 3) << 4;
    floatx4 acc[2][2] = {};
    const u16* Ap = XB + (size_t)(bm * 64 + sr) * 512 + sk;
    const u16* Bp = WCATb + (size_t)(bn * 64 + sr) * 512 + sk;
    uint4 a0 = *(const uint4*)(Ap);
    uint4 a1 = *(const uint4*)(Ap + 8);
    uint4 b0 = *(const uint4*)(Bp);
    uint4 b1 = *(const uint4*)(Bp + 8);
    for (int k0 = 0; k0 < 512; k0 += 64) {
      __syncthreads();
      *(uint4*)&As[sr][sk] = a0;
      *(uint4*)&As[sr][sk + 8] = a1;
      *(uint4*)&Bs[sr][sk] = b0;
      *(uint4*)&Bs[sr][sk + 8] = b1;
      __syncthreads();
      if (k0 + 64 < 512) {
        a0 = *(const uint4*)(Ap + k0 + 64);
        a1 = *(const uint4*)(Ap + k0 + 72);
        b0 = *(const uint4*)(Bp + k0 + 64);
        b1 = *(const uint4*)(Bp + k0 + 72);
      }
#pragma unroll
      for (int kk = 0; kk < 2; kk++) {
        short8 af0 = *(const short8*)&As[wm * 32 + l16][kk * 32 + quad * 8];
        short8 af1 = *(const short8*)&As[wm * 32 + 16 + l16][kk * 32 + quad * 8];
        short8 bf0 = *(const short8*)&Bs[wn * 32 + l16][kk * 32 + quad * 8];
        short8 bf1 = *(const short8*)&Bs[wn * 32 + 16 + l16][kk * 32 + quad * 8];
        acc[0][0] = __builtin_amdgcn_mfma_f32_16x16x32_bf16(af0, bf0, acc[0][0], 0, 0, 0);
        acc[0][1] = __builtin_amdgcn_mfma_f32_16x16x32_bf16(af0, bf1, acc[0][1], 0, 0, 0);
        acc[1][0] = __builtin_amdgcn_mfma_f32_16x16x32_bf16(af1, bf0, acc[1][0], 0, 0, 0);
        acc[1][1] = __builtin_amdgcn_mfma_f32_16x16x32_bf16(af1, bf1, acc[1][1], 0, 0, 0);
      }
    }
#pragma unroll
    for (int mt = 0; mt < 2; mt++)
#pragma unroll
      for (int r = 0; r < 4; r++) {
        int row = bm * 64 + wm * 32 + mt * 16 + quad * 4 + r;
#pragma unroll
        for (int nt = 0; nt < 2; nt++) {
          int col = bn * 64 + wn * 32 + nt * 16 + l16;
          A_QKV[(size_t)row * 1024 + col] = acc[mt][nt][r];
        }
      }
  }
  gsync(flags, rel, 1, bid, tid);

  // ======== S2: RoPE + V transpose ========
  for (int vb = bid; vb < 2560; vb += 1024) {
    if (vb < 2048) {
      int gid = vb * 256 + tid;
      int o = gid & 15;
      int t = (gid >> 4) & 2047;
      int h = (gid >> 15) & 7;
      int b = gid >> 18;
      const float* row = A_QKV + (size_t)(b * 2048 + t) * 1024;
      float freq = powf(10000.f, -(float)o / 16.f);
      float ang = (float)t * freq;
      float s, c;
      sincosf(ang, &s, &c);
      float g = qg[h] * 0.17677669529663687f;
      int qb = h * 32;
      float q0 = row[qb + o], q1 = row[qb + o + 16];
      float k0 = row[256 + qb + o], k1 = row[256 + qb + o + 16];
      u16* qo = A_Qb + ((size_t)((b * 8 + h) * 2048 + t)) * 32;
      u16* ko = A_Kb + ((size_t)((b * 8 + h) * 2048 + t)) * 32;
      qo[o] = f2b((q0 * c - q1 * s) * g);
      qo[o + 16] = f2b((q1 * c + q0 * s) * g);
      ko[o] = f2b(k0 * c - k1 * s);
      ko[o + 16] = f2b(k1 * c + k0 * s);
    } else {
      int idx = vb - 2048;
      const int tt = idx & 31, bh = idx >> 5;
      const int b = bh >> 3, h = bh & 7;
      u16 (*Ts)[72] = (u16(*)[72])SA;
      const int r = tid >> 2, q = tid & 3;
      const float* src = A_QKV + ((size_t)(b * 2048 + tt * 64 + r)) * 1024 + 512 + h * 64 + q * 16;
      __syncthreads();
#pragma unroll
      for (int j = 0; j < 4; j++) {
        float4 v = *(const float4*)(src + j * 4);
        Ts[q * 16 + j * 4 + 0][r] = f2b(v.x);
        Ts[q * 16 + j * 4 + 1][r] = f2b(v.y);
        Ts[q * 16 + j * 4 + 2][r] = f2b(v.z);
        Ts[q * 16 + j * 4 + 3][r] = f2b(v.w);
      }
      __syncthreads();
      u16* dst = A_Vt + ((size_t)(bh * 64 + r)) * 2048 + tt * 64 + q * 16;
      *(uint4*)dst = *(const uint4*)&Ts[r][q * 16];
      *(uint4*)(dst + 8) = *(const uint4*)&Ts[r][q * 16 + 8];
    }
  }
  gsync(flags, rel, 2, bid, tid);

  // ======== S3: attn split-K S=2, no-max softmax, prefetch ========
  {
    u16 (*Vts)[72] = (u16(*)[72])SA;
    u16 (*Ps)[72] = (u16(*)[72])SB;  // row = wave*16 + m
    const int bh = bid & 15;
    const int q0i = (bid >> 4) & 15;
    const int rem = bid >> 8;
    const int qt = (rem & 1) ? (31 - q0i) : q0i;
    const int s = rem >> 1;
    const int w = wave;
    const int mid = (qt + 1) >> 1;
    const int kt_beg = s ? mid : 0;
    const int kt_end = s ? (qt + 1) : mid;

    short8 qfrag = *(const short8*)(A_Qb + ((size_t)(bh * 2048 + qt * 64 + w * 16 + l16)) * 32 + quad * 8);
    floatx4 o_acc[4] = {};
    float l_part[4] = {0.f, 0.f, 0.f, 0.f};
    const u16* Kbase = A_Kb + (size_t)bh * 2048 * 32;
    const u16* Vtb = A_Vt + (size_t)bh * 64 * 2048;
    const int vr = tid >> 2, vc = (tid & 3) << 4;

    uint4 v0 = {}, v1 = {};
    short8 kf[4] = {};
    if (kt_beg < kt_end) {
      const u16* src = Vtb + (size_t)vr * 2048 + kt_beg * 64 + vc;
      v0 = *(const uint4*)src;
      v1 = *(const uint4*)(src + 8);
#pragma unroll
      for (int nt = 0; nt < 4; nt++)
        kf[nt] = *(const short8*)(Kbase + (size_t)(kt_beg * 64 + nt * 16 + l16) * 32 + quad * 8);
    }

    for (int kt = kt_beg; kt < kt_end; ++kt) {
      __syncthreads();
      *(uint4*)&Vts[vr][vc] = v0;
      *(uint4*)&Vts[vr][vc + 8] = v1;
      __syncthreads();
      const bool more = (kt + 1 < kt_end);
      uint4 v0n = {}, v1n = {};
      short8 kfn[4] = {};
      if (more) {
        const u16* src = Vtb + (size_t)vr * 2048 + (kt + 1) * 64 + vc;
        v0n = *(const uint4*)src;
        v1n = *(const uint4*)(src + 8);
#pragma unroll
        for (int nt = 0; nt < 4; nt++)
          kfn[nt] = *(const short8*)(Kbase + (size_t)((kt + 1) * 64 + nt * 16 + l16) * 32 + quad * 8);
      }

      floatx4 s_acc[4];
#pragma unroll
      for (int nt = 0; nt < 4; nt++) {
        floatx4 zz = {0.f, 0.f, 0.f, 0.f};
        s_acc[nt] = __builtin_amdgcn_mfma_f32_16x16x32_bf16(qfrag, kf[nt], zz, 0, 0, 0);
      }
      const bool diag = (kt == qt);
#pragma unroll
      for (int r = 0; r < 4; r++) {
        int mloc = w * 16 + quad * 4 + r;
        float psum = 0.f;
#pragma unroll
        for (int nt = 0; nt < 4; nt++) {
          float p = __expf(s_acc[nt][r]);
          if (diag && (nt * 16 + l16) > mloc) p = 0.f;
          psum += p;
          Ps[w * 16 + quad * 4 + r][nt * 16 + l16] = f2b(p);
        }
        l_part[r] += psum;
      }
#pragma unroll
      for (int kc = 0; kc < 2; kc++) {
        short8 pf = *(const short8*)&Ps[w * 16 + l16][kc * 32 + quad * 8];
#pragma unroll
        for (int nt = 0; nt < 4; nt++) {
          short8 vf = *(const short8*)&Vts[nt * 16 + l16][kc * 32 + quad * 8];
          o_acc[nt] = __builtin_amdgcn_mfma_f32_16x16x32_bf16(pf, vf, o_acc[nt], 0, 0, 0);
        }
      }
      v0 = v0n; v1 = v1n;
#pragma unroll
      for (int nt = 0; nt < 4; nt++) kf[nt] = kfn[nt];
    }

    const int pidx = (bh * 32 + qt) * 2 + s;
    float* pob = A_PO + (size_t)pidx * 4096;
#pragma unroll
    for (int r = 0; r < 4; r++) {
      float ls = l_part[r];
#pragma unroll
      for (int mk = 1; mk < 16; mk <<= 1) ls += __shfl_xor(ls, mk, 64);
      int row = w * 16 + quad * 4 + r;
#pragma unroll
      for (int nt = 0; nt < 4; nt++) pob[row * 64 + nt * 16 + l16] = o_acc[nt][r];
      if (l16 == 0) A_PL[pidx * 64 + row] = ls;
    }
  }
  gsync(flags, rel, 3, bid, tid);

  // ======== S4: combine + self-align (32 rows per block) ========
  for (int j = 0; j < 8; j++) {
    int ridx = bid * 32 + j * 4 + wave;
    int bh = ridx >> 11, tok = ridx & 2047;
    int qt = tok >> 6, row = tok & 63;
    int pidx = (bh * 32 + qt) * 2;
    const float* p0 = A_PO + (size_t)pidx * 4096 + row * 64;
    float o = p0[lane] + p0[4096 + lane];
    float l = A_PL[pidx * 64 + row] + A_PL[(pidx + 1) * 64 + row];
    float yv = o / l;
    int b = bh >> 3, h = bh & 7;
    float vv = A_QKV[(size_t)(b * 2048 + tok) * 1024 + 512 + h * 64 + lane];
    float ss = vv * vv, dot = yv * vv;
#pragma unroll
    for (int mk = 1; mk < 64; mk <<= 1) {
      ss += __shfl_xor(ss, mk, 64);
      dot += __shfl_xor(dot, mk, 64);
    }
    float coef = dot / fmaxf(ss, 1e-24f);
    A_Y2b[(size_t)(b * 2048 + tok) * 512 + h * 64 + lane] = f2b(yv - coef * vv);
  }
  gsync(flags, rel, 4, bid, tid);

  // ======== S5..S10: the 4 chain GEMMs (32x64 tile) + 2 LNs ========
  {
    u16 (*As)[72] = (u16(*)[72])SA;
    u16 (*Bs)[72] = (u16(*)[72])SB;
    const int bn = bid & 7, bm = bid >> 3;
    const int wm = wave >> 1, wn = wave & 1;
    const int ar = tid >> 3, ak = (tid & 7) << 3;
    const int br = tid >> 2, bk = (tid & 3) << 4;

#define GEMM32(Aptr, Bptr, Xptr, Cptr, Cbptr, EPI, DUAL)                                       \
    {                                                                                          \
      floatx4 acc[2] = {};                                                                     \
      const u16* Ap = (Aptr) + (size_t)(bm * 32 + ar) * 512 + ak;                              \
      const u16* Bp = (Bptr) + (size_t)(bn * 64 + br) * 512 + bk;                              \
      uint4 a0 = *(const uint4*)(Ap);                                                          \
      uint4 b0 = *(const uint4*)(Bp);                                                          \
      uint4 b1 = *(const uint4*)(Bp + 8);                                                      \
      for (int k0 = 0; k0 < 512; k0 += 64) {                                                   \
        __syncthreads();                                                                       \
        *(uint4*)&As[ar][ak] = a0;                                                             \
        *(uint4*)&Bs[br][bk] = b0;                                                             \
        *(uint4*)&Bs[br][bk + 8] = b1;                                                         \
        __syncthreads();                                                                       \
        if (k0 + 64 < 512) {                                                                   \
          a0 = *(const uint4*)(Ap + k0 + 64);                                                  \
          b0 = *(const uint4*)(Bp + k0 + 64);                                                  \
          b1 = *(const uint4*)(Bp + k0 + 72);                                                  \
        }                                                                                      \
        _Pragma("unroll")                                                                      \
        for (int kk = 0; kk < 2; kk++) {                                                       \
          short8 af = *(const short8*)&As[wm * 16 + l16][kk * 32 + quad * 8];                  \
          short8 bf0 = *(const short8*)&Bs[wn * 32 + l16][kk * 32 + quad * 8];                 \
          short8 bf1 = *(const short8*)&Bs[wn * 32 + 16 + l16][kk * 32 + quad * 8];            \
          acc[0] = __builtin_amdgcn_mfma_f32_16x16x32_bf16(af, bf0, acc[0], 0, 0, 0);          \
          acc[1] = __builtin_amdgcn_mfma_f32_16x16x32_bf16(af, bf1, acc[1], 0, 0, 0);          \
        }                                                                                      \
      }                                                                                        \
      _Pragma("unroll")                                                                        \
      for (int r = 0; r < 4; r++) {                                                            \
        int row = bm * 32 + wm * 16 + quad * 4 + r;                                            \
        _Pragma("unroll")                                                                      \
        for (int nt = 0; nt < 2; nt++) {                                                       \
          int col = bn * 64 + wn * 32 + nt * 16 + l16;                                         \
          float v = acc[nt][r];                                                                \
          if (EPI == 1) {                                                                      \
            v += (Xptr)[(size_t)row * 512 + col];                                              \
          } else if (EPI == 2) {                                                               \
            float xv = (Xptr)[(size_t)row * 512 + col];                                        \
            v = xv + v / (1.f + __expf(-v));                                                   \
          }                                                                                    \
          (Cptr)[(size_t)row * 512 + col] = v;                                                 \
          if (DUAL) (Cbptr)[(size_t)row * 512 + col] = f2b(v);                                 \
        }                                                                                      \
      }                                                                                        \
    }

#define LN_STAGE(inptr, gptr, bptr, outptr)                                                    \
    {                                                                                          \
      int row = bid * 4 + wave;                                                                \
      const float* rp = (inptr) + (size_t)row * 512 + lane * 8;                                \
      float4 aa = *(const float4*)rp;                                                          \
      float4 bb = *(const float4*)(rp + 4);                                                    \
      float v[8] = {aa.x, aa.y, aa.z, aa.w, bb.x, bb.y, bb.z, bb.w};                           \
      float s = 0.f;                                                                           \
      _Pragma("unroll") for (int e = 0; e < 8; e++) s += v[e];                                 \
      _Pragma("unroll") for (int mk = 1; mk < 64; mk <<= 1) s += __shfl_xor(s, mk, 64);        \
      float mean = s * (1.f / 512.f);                                                          \
      float vs = 0.f;                                                                          \
      _Pragma("unroll") for (int e = 0; e < 8; e++) { float d = v[e] - mean; vs = fmaf(d, d, vs); } \
      _Pragma("unroll") for (int mk = 1; mk < 64; mk <<= 1) vs += __shfl_xor(vs, mk, 64);      \
      float inv = rsqrtf(vs * (1.f / 512.f) + 1e-5f);                                          \
      int c0 = lane * 8;                                                                       \
      u16* op = (outptr) + (size_t)row * 512 + c0;                                             \
      ushort4 o1, o2;                                                                          \
      o1.x = f2b((v[0] - mean) * inv * (gptr)[c0 + 0] + (bptr)[c0 + 0]);                       \
      o1.y = f2b((v[1] - mean) * inv * (gptr)[c0 + 1] + (bptr)[c0 + 1]);                       \
      o1.z = f2b((v[2] - mean) * inv * (gptr)[c0 + 2] + (bptr)[c0 + 2]);                       \
      o1.w = f2b((v[3] - mean) * inv * (gptr)[c0 + 3] + (bptr)[c0 + 3]);                       \
      o2.x = f2b((v[4] - mean) * inv * (gptr)[c0 + 4] + (bptr)[c0 + 4]);                       \
      o2.y = f2b((v[5] - mean) * inv * (gptr)[c0 + 5] + (bptr)[c0 + 5]);                       \
      o2.z = f2b((v[6] - mean) * inv * (gptr)[c0 + 6] + (bptr)[c0 + 6]);                       \
      o2.w = f2b((v[7] - mean) * inv * (gptr)[c0 + 7] + (bptr)[c0 + 7]);                       \
      *(ushort4*)op = o1;                                                                      \
      *(ushort4*)(op + 4) = o2;                                                                \
    }

    GEMM32(A_Y2b, WPRb, x, A_H, A_Hb, 1, true);          // h = y2 @ wpr^T + x
    gsync(flags, rel, 5, bid, tid);
    GEMM32(A_Hb, W0b, x, A_QKV, A_Hb, 0, false);         // he0 = h @ w0^T
    gsync(flags, rel, 6, bid, tid);
    LN_STAGE(A_QKV, g1, b1, A_LNb);                      // ln1
    gsync(flags, rel, 7, bid, tid);
    GEMM32(A_LNb, W1b, A_H, A_Y, A_Hb, 2, false);        // he1 = h + silu(ln1 @ w1^T)
    gsync(flags, rel, 8, bid, tid);
    LN_STAGE(A_Y, g2, b2, A_LNb);                        // ln2
    gsync(flags, rel, 9, bid, tid);
    GEMM32(A_LNb, W2b, A_Y, A_HE2, A_Hb, 2, false);      // he2 = he1 + silu(ln2 @ w2^T)
    gsync(flags, rel, 10, bid, tid);
  }

  // ======== S11: RMS + 512->32 projection + softplus/tanh ========
  if (bid < 512) {
    int tok = bid * 8 + (tid >> 5);
    int n = tid & 31;
    const float* rr = A_HE2 + (size_t)tok * 512;
    float ss = 0.f;
#pragma unroll
    for (int j = 0; j < 4; j++) {
      float4 v = ((const float4*)rr)[j * 32 + n];
      ss = fmaf(v.x, v.x, fmaf(v.y, v.y, fmaf(v.z, v.z, fmaf(v.w, v.w, ss))));
    }
#pragma unroll
    for (int mk = 1; mk < 32; mk <<= 1) ss += __shfl_xor(ss, mk, 64);
    float rinv = rsqrtf(ss * (1.f / 512.f) + 1e-6f);
    const float* w = wout + (size_t)n * 512;
    float acc = 0.f;
    for (int d = 0; d < 512; d += 4) {
      float4 rv = *(const float4*)(rr + d);
      float4 wv = *(const float4*)(w + d);
      acc = fmaf(rv.x, wv.x, acc);
      acc = fmaf(rv.y, wv.y, acc);
      acc = fmaf(rv.z, wv.z, acc);
      acc = fmaf(rv.w, wv.w, acc);
    }
    float c = ct[n];
    float sp = (c > 20.f) ? c : log1pf(__expf(c));
    z[(size_t)tok * 32 + n] = tanhf(acc * rinv / (sp + 1e-4f));
  }
}

extern "C" void kernel_launch(void* const* d_in, const int* in_sizes, int n_in,
                              void* d_out, int out_size, void* d_ws, size_t ws_size,
                              hipStream_t stream) {
  const float* x = (const float*)d_in[0];
  const float* qp = (const float*)d_in[1];
  const float* kp = (const float*)d_in[2];
  const float* wv = (const float*)d_in[3];
  const float* wpr = (const float*)d_in[4];
  const float* qg = (const float*)d_in[5];
  const float* w0 = (const float*)d_in[6];
  const float* g1 = (const float*)d_in[7];
  const float* b1 = (const float*)d_in[8];
  const float* w1 = (const float*)d_in[9];
  const float* g2 = (const float*)d_in[10];
  const float* b2 = (const float*)d_in[11];
  const float* w2 = (const float*)d_in[12];
  const float* wout = (const float*)d_in[13];
  const float* ct = (const float*)d_in[14];
  float* z = (float*)d_out;
  float* ws = (float*)d_ws;

  unsigned* flags = (unsigned*)(ws + 30 * 1024 * 1024);  // 1024 u32
  unsigned* rel = flags + 1024;                          // 11 slots x 32 u32
  hipMemsetAsync(flags, 0, (1024 + 11 * 32) * sizeof(unsigned), stream);
  hipLaunchKernelGGL(mega, dim3(1024), dim3(256), 0, stream,
                     x, qp, kp, wv, wpr, qg, w0, g1, b1, w1, g2, b2, w2, wout, ct, z, ws,
                     flags, rel);
}